// Round 1
// baseline (222.366 us; speedup 1.0000x reference)
//
#include <hip/hip_runtime.h>
#include <hip/hip_cooperative_groups.h>
#include <math.h>

namespace cg = cooperative_groups;

#define EPS 1e-8f
#define NPTS 24
#define NREG 64            // worklist regions (counter spread)
#define CTR_STRIDE 64      // u32 units -> 256B between counters

// ---- constexpr Batcher odd-even mergesort comparator network for NPTS=24 ----
struct Net {
    int n;
    unsigned char lo[256];
    unsigned char hi[256];
};
constexpr Net build_net() {
    Net net{};
    net.n = 0;
    for (int p = 1; p < NPTS; p <<= 1)
        for (int k = p; k >= 1; k >>= 1)
            for (int j = k % p; j + k < NPTS; j += 2 * k)
                for (int i = 0; i < k && i + j + k < NPTS; ++i)
                    if ((i + j) / (2 * p) == (i + j + k) / (2 * p)) {
                        net.lo[net.n] = (unsigned char)(i + j);
                        net.hi[net.n] = (unsigned char)(i + j + k);
                        ++net.n;
                    }
    return net;
}
constexpr Net NET = build_net();

// ---- the verified heavy path: exact area for one pair ----
__device__ __forceinline__ float pair_area(const float* __restrict__ A,
                                           const float* __restrict__ B)
{
    float ax = A[0], ay = A[1], adx = A[3], ady = A[4], ayaw = A[6];
    float bx = B[0], by = B[1], bdx = B[3], bdy = B[4], byaw = B[6];

    float ca = __builtin_cosf(ayaw), sa = __builtin_sinf(ayaw);
    float cb = __builtin_cosf(byaw), sb = __builtin_sinf(byaw);

    const float tx[4] = {0.5f, 0.5f, -0.5f, -0.5f};
    const float ty[4] = {0.5f, -0.5f, -0.5f, 0.5f};

    float cax[4], cay[4], cbx[4], cby[4];
#pragma unroll
    for (int k = 0; k < 4; ++k) {
        float lx = tx[k] * adx, ly = ty[k] * ady;
        cax[k] = lx * ca - ly * sa + ax;
        cay[k] = lx * sa + ly * ca + ay;
        lx = tx[k] * bdx; ly = ty[k] * bdy;
        cbx[k] = lx * cb - ly * sb + bx;
        cby[k] = lx * sb + ly * cb + by;
    }

    float px[NPTS], py[NPTS];
    bool valid[NPTS];

#pragma unroll
    for (int k = 0; k < 4; ++k) {
        float relx = cax[k] - bx, rely = cay[k] - by;
        float rx = relx * cb + rely * sb;
        float ry = -relx * sb + rely * cb;
        valid[k] = (fabsf(rx) <= bdx * 0.5f + 1e-5f) &&
                   (fabsf(ry) <= bdy * 0.5f + 1e-5f);
        px[k] = cax[k]; py[k] = cay[k];
    }
#pragma unroll
    for (int k = 0; k < 4; ++k) {
        float relx = cbx[k] - ax, rely = cby[k] - ay;
        float rx = relx * ca + rely * sa;
        float ry = -relx * sa + rely * ca;
        valid[4 + k] = (fabsf(rx) <= adx * 0.5f + 1e-5f) &&
                       (fabsf(ry) <= ady * 0.5f + 1e-5f);
        px[4 + k] = cbx[k]; py[4 + k] = cby[k];
    }

#pragma unroll
    for (int a = 0; a < 4; ++a) {
        int a2 = (a + 1) & 3;
        float p1x = cax[a], p1y = cay[a];
        float d1x = cax[a2] - p1x, d1y = cay[a2] - p1y;
#pragma unroll
        for (int b = 0; b < 4; ++b) {
            int b2 = (b + 1) & 3;
            float q1x = cbx[b], q1y = cby[b];
            float d2x = cbx[b2] - q1x, d2y = cby[b2] - q1y;
            float denom = d1x * d2y - d1y * d2x;
            bool dok = fabsf(denom) > EPS;
            float safe = dok ? denom : 1.0f;
            float inv = __builtin_amdgcn_rcpf(safe);
            float dqx = q1x - p1x, dqy = q1y - p1y;
            float t = (dqx * d2y - dqy * d2x) * inv;
            float u = (dqx * d1y - dqy * d1x) * inv;
            bool v = dok && (t >= 0.0f) && (t <= 1.0f) && (u >= 0.0f) && (u <= 1.0f);
            int o = 8 + a * 4 + b;
            px[o] = p1x + t * d1x;
            py[o] = p1y + t * d1y;
            valid[o] = v;
        }
    }

    int cnt = 0;
    float sx = 0.0f, sy = 0.0f;
#pragma unroll
    for (int k = 0; k < NPTS; ++k) {
        if (valid[k]) cnt++;
        float w = valid[k] ? 1.0f : 0.0f;
        sx += px[k] * w;
        sy += py[k] * w;
    }
    float cntf = (float)(cnt > 1 ? cnt : 1);
    float cx_ = sx / cntf, cy_ = sy / cntf;

    unsigned key[NPTS];
#pragma unroll
    for (int k = 0; k < NPTS; ++k) {
        float rx = px[k] - cx_, ry = py[k] - cy_;
        float axx = fabsf(rx), ayy = fabsf(ry);
        float d = fmaxf(axx + ayy, 1e-30f);
        float r = ry * __builtin_amdgcn_rcpf(d);
        float t = (rx >= 0.0f) ? r : ((ry >= 0.0f) ? 2.0f - r : -2.0f - r);
        unsigned u = __float_as_uint(t);
        unsigned ordered = u ^ ((unsigned)((int)u >> 31) | 0x80000000u);
        key[k] = valid[k] ? ((ordered & 0xFFFFFFE0u) | (unsigned)k)
                          : (0xFFFFFF00u | (unsigned)k);
    }

#pragma unroll
    for (int c = 0; c < NET.n; ++c) {
        int lo = NET.lo[c], hi = NET.hi[c];
        bool sw = key[hi] < key[lo];
        unsigned kl = key[lo], kh = key[hi];
        float xl = px[lo], xh = px[hi];
        float yl = py[lo], yh = py[hi];
        key[lo] = sw ? kh : kl;  key[hi] = sw ? kl : kh;
        px[lo]  = sw ? xh : xl;  px[hi]  = sw ? xl : xh;
        py[lo]  = sw ? yh : yl;  py[hi]  = sw ? yl : yh;
    }

    float lastx = 0.0f, lasty = 0.0f;
#pragma unroll
    for (int r = 0; r < NPTS; ++r) {
        bool isLast = (r == cnt - 1);
        lastx = isLast ? px[r] : lastx;
        lasty = isLast ? py[r] : lasty;
    }

    float s = 0.0f;
#pragma unroll
    for (int r = 0; r + 1 < NPTS; ++r) {
        float cr = px[r] * py[r + 1] - px[r + 1] * py[r];
        s += (r + 1 < cnt) ? cr : 0.0f;
    }
    s += (cnt >= 1) ? (lastx * py[0] - px[0] * lasty) : 0.0f;

    float area = 0.5f * fabsf(s);
    return (cnt >= 3) ? area : 0.0f;
}

// ============================================================================
// NEW: single cooperative kernel. 1 wave per block.
// Phase 1: 4 pairs/thread cull (float4 zero-stores for non-survivors only),
//          per-wave ballot compaction, one atomic per wave-iter into 64
//          region counters (pre-zeroed by a hipMemsetAsync node).
// grid.sync()
// Phase 2: dense per-region processing of survivors (same as process_kernel).
// Phase-1 zero-stores and phase-2 area-stores are address-disjoint, so
// cross-XCD L2 non-coherence cannot produce conflicting dirty lines.
// ============================================================================
__global__ __launch_bounds__(64) void fused_kernel(
    const float* __restrict__ boxes, float* __restrict__ out,
    unsigned* __restrict__ counters, unsigned* __restrict__ regions,
    int m, int n, unsigned reg_cap, unsigned magic)
{
    const unsigned n4 = (unsigned)(n >> 2);
    const unsigned NQ = (unsigned)m * n4;            // total j-quads
    const unsigned NT = gridDim.x * 64u;             // total threads
    const unsigned g  = blockIdx.x * 64u + threadIdx.x;
    const unsigned w  = blockIdx.x;                  // wave id (1 wave/block)
    const int lane    = (int)threadIdx.x;            // 0..63
    const unsigned region = w & (NREG - 1);
    const unsigned long long below = (1ull << lane) - 1ull;

    // ---------------- phase 1: cull ----------------
    for (unsigned q = g; q < NQ; q += NT) {
        unsigned i  = (unsigned)(((unsigned long long)q * magic) >> 32);
        unsigned jq = q - i * n4;
        unsigned j0 = jq * 4u;

        const float* bi = boxes + (size_t)i * 7;
        float xi = bi[0], yi = bi[1];
        float dxi = bi[3], dyi = bi[4];
        float ri = 0.5f * sqrtf(dxi * dxi + dyi * dyi) + 0.005f;

        bool keep[4];
#pragma unroll
        for (int k = 0; k < 4; ++k) {
            const float* bj = boxes + (size_t)(m + j0 + k) * 7;
            float xj = bj[0], yj = bj[1];
            float dxj = bj[3], dyj = bj[4];
            float rj = 0.5f * sqrtf(dxj * dxj + dyj * dyj) + 0.005f;
            float ddx = xi - xj, ddy = yi - yj, rr = ri + rj;
            keep[k] = (ddx * ddx + ddy * ddy) <= rr * rr;
        }

        // zero only non-survivor slots (disjoint from phase-2 writes)
        float* orow = out + (size_t)i * n + j0;
        int km = (keep[0] ? 1 : 0) | (keep[1] ? 2 : 0) |
                 (keep[2] ? 4 : 0) | (keep[3] ? 8 : 0);
        if (km == 0) {
            *(float4*)orow = make_float4(0.0f, 0.0f, 0.0f, 0.0f);
        } else {
#pragma unroll
            for (int k = 0; k < 4; ++k) if (!keep[k]) orow[k] = 0.0f;
        }

        // wave compaction: 4 ballots, one atomic
        unsigned long long mk[4];
        int c[4];
#pragma unroll
        for (int k = 0; k < 4; ++k) {
            mk[k] = __ballot(keep[k]);
            c[k] = __popcll(mk[k]);
        }
        int ctot = c[0] + c[1] + c[2] + c[3];
        if (__builtin_amdgcn_readfirstlane(ctot) || ctot) {   // wave-uniform value
            if (ctot > 0) { /* ctot is wave-uniform by construction */ }
        }
        if (ctot > 0) {
            unsigned base = 0;
            if (lane == 0)
                base = atomicAdd(&counters[region * CTR_STRIDE], (unsigned)ctot);
            base = (unsigned)__shfl((int)base, 0, 64);
            unsigned* seg = regions + (size_t)region * reg_cap;
            int pre = 0;
#pragma unroll
            for (int k = 0; k < 4; ++k) {
                if (keep[k]) {
                    int rank = pre + __popcll(mk[k] & below);
                    seg[base + rank] = (i << 12) | (j0 + (unsigned)k);
                }
                pre += c[k];
            }
        }
    }

    __threadfence();
    cg::this_grid().sync();

    // ---------------- phase 2: process survivors ----------------
    unsigned cnt = counters[region * CTR_STRIDE];
    unsigned slice = w >> 6;                       // which 64-lane slice of region
    unsigned nserv = gridDim.x >> 6;               // waves serving each region
    const unsigned* seg = regions + (size_t)region * reg_cap;
    for (unsigned t = slice * 64u + (unsigned)lane; t < cnt; t += nserv * 64u) {
        unsigned v = seg[t];
        int i = (int)(v >> 12);
        int j = (int)(v & 4095u);
        const float* A = boxes + (size_t)i * 7;
        const float* B = boxes + (size_t)(m + j) * 7;
        out[(size_t)i * n + j] = pair_area(A, B);
    }
}

// ============================================================================
// Fallback pipeline (verified at 23.65 us) — unchanged.
// ============================================================================
__global__ __launch_bounds__(256) void prep_kernel(
    const float* __restrict__ boxes, float* __restrict__ xs,
    float* __restrict__ ys, float* __restrict__ rs,
    unsigned* __restrict__ counters, int total)
{
    int t = blockIdx.x * blockDim.x + threadIdx.x;
    if (t < NREG * CTR_STRIDE) counters[t] = 0;
    if (t < total) {
        float dx = boxes[(size_t)t * 7 + 3];
        float dy = boxes[(size_t)t * 7 + 4];
        xs[t] = boxes[(size_t)t * 7 + 0];
        ys[t] = boxes[(size_t)t * 7 + 1];
        rs[t] = 0.5f * sqrtf(dx * dx + dy * dy) + 0.005f;
    }
}

__global__ __launch_bounds__(256) void cull_kernel(
    const float* __restrict__ xs, const float* __restrict__ ys,
    const float* __restrict__ rs, float* __restrict__ out,
    unsigned* __restrict__ counters, unsigned* __restrict__ regions,
    int m, int n, unsigned reg_cap)
{
    int jb = blockIdx.x, i = blockIdx.y;
    int tid = threadIdx.x;
    int j = jb * 256 + tid;

    bool keep = false;
    if (j < n) {
        float dx = xs[i] - xs[m + j];
        float dy = ys[i] - ys[m + j];
        float rr = rs[i] + rs[m + j];
        keep = (dx * dx + dy * dy) <= rr * rr;
        out[(size_t)i * n + j] = 0.0f;
    }

    unsigned long long mask = __ballot(keep);
    if (mask == 0ull) return;

    int lane = tid & 63;
    unsigned gwid = ((unsigned)(i * gridDim.x + jb) << 2) | ((unsigned)tid >> 6);
    unsigned region = gwid & (NREG - 1);

    int c = __popcll(mask);
    int lead = __ffsll((unsigned long long)mask) - 1;
    unsigned pos = 0;
    if (lane == lead) pos = atomicAdd(&counters[region * CTR_STRIDE], (unsigned)c);
    pos = (unsigned)__shfl((int)pos, lead, 64);
    if (keep) {
        int rank = __popcll(mask & ((1ull << lane) - 1ull));
        regions[(size_t)region * reg_cap + pos + rank] =
            ((unsigned)i << 12) | (unsigned)j;
    }
}

__global__ __launch_bounds__(64) void process_kernel(
    const float* __restrict__ boxes, float* __restrict__ out,
    const unsigned* __restrict__ counters, const unsigned* __restrict__ regions,
    int m, int n, unsigned reg_cap)
{
    unsigned region = blockIdx.x >> 2;
    unsigned cnt = counters[region * CTR_STRIDE];
    const unsigned* seg = regions + (size_t)region * reg_cap;
    for (unsigned t = ((blockIdx.x & 3u) << 6) | threadIdx.x; t < cnt; t += 256) {
        unsigned v = seg[t];
        int i = (int)(v >> 12);
        int j = (int)(v & 4095u);
        const float* A = boxes + (size_t)i * 7;
        const float* B = boxes + (size_t)(m + j) * 7;
        out[(size_t)i * n + j] = pair_area(A, B);
    }
}

__global__ __launch_bounds__(256) void overlap_kernel(
    const float* __restrict__ boxes, float* __restrict__ out, int m, int n)
{
    int j = blockIdx.x * blockDim.x + threadIdx.x;
    int i = blockIdx.y;
    if (j >= n) return;
    const float* A = boxes + (size_t)i * 7;
    const float* B = boxes + (size_t)(m + j) * 7;
    out[(size_t)i * n + j] = pair_area(A, B);
}

extern "C" void kernel_launch(void* const* d_in, const int* in_sizes, int n_in,
                              void* d_out, int out_size, void* d_ws, size_t ws_size,
                              hipStream_t stream) {
    const float* boxes = (const float*)d_in[0];
    float* out = (float*)d_out;
    int total = in_sizes[0] / 7;   // 3000 boxes
    int m = total / 3;             // 1000
    int n = total - m;             // 2000

    // ---------------- cooperative fused path ----------------
    static int coop_blocks = -2;           // -2 = not queried, -1 = unavailable
    static bool coop_failed = false;
    if (coop_blocks == -2) {
        int occ = 0;
        hipError_t e1 = hipOccupancyMaxActiveBlocksPerMultiprocessor(
            &occ, (const void*)fused_kernel, 64, 0);
        int dev = 0;
        hipGetDevice(&dev);
        hipDeviceProp_t prop;
        hipError_t e2 = hipGetDeviceProperties(&prop, dev);
        coop_blocks = (e1 == hipSuccess && e2 == hipSuccess && occ > 0)
                          ? occ * prop.multiProcessorCount
                          : -1;
    }

    bool coop_ok = !coop_failed && coop_blocks >= 64 &&
                   (n % 4 == 0) && (n <= 4095) && m >= 1;
    unsigned magic = 0, NQ = 0, reg_cap2 = 0;
    int NB = 0;
    if (coop_ok) {
        unsigned d = (unsigned)(n / 4);
        NQ = (unsigned)m * d;
        unsigned long long two32 = 1ull << 32;
        unsigned r = (unsigned)(two32 % d);
        if (r == 0) {
            magic = (unsigned)(two32 / d);
        } else {
            magic = (unsigned)(two32 / d) + 1u;
            if ((unsigned long long)(NQ - 1) * (unsigned long long)(d - r) >= two32)
                coop_ok = false;           // magic-div not exact for this range
        }
        NB = coop_blocks < 2048 ? coop_blocks : 2048;
        NB &= ~63;                         // multiple of 64 (region math)
        if (NB < 64) coop_ok = false;
        if (coop_ok) {
            unsigned nt = (unsigned)NB * 64u;
            unsigned niters = (NQ + nt - 1) / nt;
            reg_cap2 = (unsigned)(NB / 64) * niters * 256u;   // hard upper bound
            size_t need = (size_t)NREG * CTR_STRIDE * 4 +
                          (size_t)NREG * reg_cap2 * 4;
            if (ws_size < need) coop_ok = false;
        }
    }

    if (coop_ok) {
        unsigned* counters = (unsigned*)d_ws;
        unsigned* regions  = (unsigned*)((char*)d_ws + (size_t)NREG * CTR_STRIDE * 4);
        hipError_t e = hipMemsetAsync(counters, 0,
                                      (size_t)NREG * CTR_STRIDE * 4, stream);
        if (e == hipSuccess) {
            void* args[8];
            args[0] = (void*)&boxes;
            args[1] = (void*)&out;
            args[2] = (void*)&counters;
            args[3] = (void*)&regions;
            args[4] = (void*)&m;
            args[5] = (void*)&n;
            args[6] = (void*)&reg_cap2;
            args[7] = (void*)&magic;
            e = hipLaunchCooperativeKernel((const void*)fused_kernel,
                                           dim3((unsigned)NB), dim3(64),
                                           args, 0, stream);
            if (e == hipSuccess) return;
        }
        coop_failed = true;   // don't retry a failing path
        // fall through to the verified 3-kernel pipeline
    }

    // ---------------- fallback: verified 3-kernel pipeline ----------------
    int bpr = (n + 255) / 256;
    unsigned total_waves = (unsigned)(bpr * m) * 4u;
    unsigned reg_cap = ((total_waves + NREG - 1) / NREG) * 64u;

    size_t ctr_off = 0;
    size_t xs_off  = ctr_off + (size_t)NREG * CTR_STRIDE * 4;
    size_t ys_off  = xs_off + (size_t)total * 4;
    size_t rs_off  = ys_off + (size_t)total * 4;
    size_t reg_off = ((rs_off + (size_t)total * 4) + 255) & ~(size_t)255;
    size_t need    = reg_off + (size_t)NREG * reg_cap * 4;

    if (ws_size < need) {
        dim3 block(256, 1, 1);
        dim3 grid((n + 255) / 256, m, 1);
        hipLaunchKernelGGL(overlap_kernel, grid, block, 0, stream, boxes, out, m, n);
        return;
    }

    unsigned* counters = (unsigned*)((char*)d_ws + ctr_off);
    float* xs = (float*)((char*)d_ws + xs_off);
    float* ys = (float*)((char*)d_ws + ys_off);
    float* rs = (float*)((char*)d_ws + rs_off);
    unsigned* regions = (unsigned*)((char*)d_ws + reg_off);

    int prep_threads = (NREG * CTR_STRIDE > total) ? NREG * CTR_STRIDE : total;
    hipLaunchKernelGGL(prep_kernel, dim3((prep_threads + 255) / 256), dim3(256),
                       0, stream, boxes, xs, ys, rs, counters, total);

    hipLaunchKernelGGL(cull_kernel, dim3(bpr, m, 1), dim3(256), 0, stream,
                       xs, ys, rs, out, counters, regions, m, n, reg_cap);

    hipLaunchKernelGGL(process_kernel, dim3(NREG * 4, 1, 1), dim3(64), 0, stream,
                       boxes, out, counters, regions, m, n, reg_cap);
}

// Round 2
// 93.790 us; speedup vs baseline: 2.3709x; 2.3709x over previous
//
#include <hip/hip_runtime.h>
#include <math.h>

#define EPS 1e-8f
#define NPTS 24
#define NREG 64            // worklist regions (counter spread)
#define CTR_STRIDE 64      // u32 units -> 256B between counters

// ---- constexpr Batcher odd-even mergesort comparator network for NPTS=24 ----
struct Net {
    int n;
    unsigned char lo[256];
    unsigned char hi[256];
};
constexpr Net build_net() {
    Net net{};
    net.n = 0;
    for (int p = 1; p < NPTS; p <<= 1)
        for (int k = p; k >= 1; k >>= 1)
            for (int j = k % p; j + k < NPTS; j += 2 * k)
                for (int i = 0; i < k && i + j + k < NPTS; ++i)
                    if ((i + j) / (2 * p) == (i + j + k) / (2 * p)) {
                        net.lo[net.n] = (unsigned char)(i + j);
                        net.hi[net.n] = (unsigned char)(i + j + k);
                        ++net.n;
                    }
    return net;
}
constexpr Net NET = build_net();

// ---- the verified heavy path: exact area for one pair ----
__device__ __forceinline__ float pair_area(const float* __restrict__ A,
                                           const float* __restrict__ B)
{
    float ax = A[0], ay = A[1], adx = A[3], ady = A[4], ayaw = A[6];
    float bx = B[0], by = B[1], bdx = B[3], bdy = B[4], byaw = B[6];

    float ca = __builtin_cosf(ayaw), sa = __builtin_sinf(ayaw);
    float cb = __builtin_cosf(byaw), sb = __builtin_sinf(byaw);

    const float tx[4] = {0.5f, 0.5f, -0.5f, -0.5f};
    const float ty[4] = {0.5f, -0.5f, -0.5f, 0.5f};

    float cax[4], cay[4], cbx[4], cby[4];
#pragma unroll
    for (int k = 0; k < 4; ++k) {
        float lx = tx[k] * adx, ly = ty[k] * ady;
        cax[k] = lx * ca - ly * sa + ax;
        cay[k] = lx * sa + ly * ca + ay;
        lx = tx[k] * bdx; ly = ty[k] * bdy;
        cbx[k] = lx * cb - ly * sb + bx;
        cby[k] = lx * sb + ly * cb + by;
    }

    float px[NPTS], py[NPTS];
    bool valid[NPTS];

#pragma unroll
    for (int k = 0; k < 4; ++k) {
        float relx = cax[k] - bx, rely = cay[k] - by;
        float rx = relx * cb + rely * sb;
        float ry = -relx * sb + rely * cb;
        valid[k] = (fabsf(rx) <= bdx * 0.5f + 1e-5f) &&
                   (fabsf(ry) <= bdy * 0.5f + 1e-5f);
        px[k] = cax[k]; py[k] = cay[k];
    }
#pragma unroll
    for (int k = 0; k < 4; ++k) {
        float relx = cbx[k] - ax, rely = cby[k] - ay;
        float rx = relx * ca + rely * sa;
        float ry = -relx * sa + rely * ca;
        valid[4 + k] = (fabsf(rx) <= adx * 0.5f + 1e-5f) &&
                       (fabsf(ry) <= ady * 0.5f + 1e-5f);
        px[4 + k] = cbx[k]; py[4 + k] = cby[k];
    }

#pragma unroll
    for (int a = 0; a < 4; ++a) {
        int a2 = (a + 1) & 3;
        float p1x = cax[a], p1y = cay[a];
        float d1x = cax[a2] - p1x, d1y = cay[a2] - p1y;
#pragma unroll
        for (int b = 0; b < 4; ++b) {
            int b2 = (b + 1) & 3;
            float q1x = cbx[b], q1y = cby[b];
            float d2x = cbx[b2] - q1x, d2y = cby[b2] - q1y;
            float denom = d1x * d2y - d1y * d2x;
            bool dok = fabsf(denom) > EPS;
            float safe = dok ? denom : 1.0f;
            float inv = __builtin_amdgcn_rcpf(safe);
            float dqx = q1x - p1x, dqy = q1y - p1y;
            float t = (dqx * d2y - dqy * d2x) * inv;
            float u = (dqx * d1y - dqy * d1x) * inv;
            bool v = dok && (t >= 0.0f) && (t <= 1.0f) && (u >= 0.0f) && (u <= 1.0f);
            int o = 8 + a * 4 + b;
            px[o] = p1x + t * d1x;
            py[o] = p1y + t * d1y;
            valid[o] = v;
        }
    }

    int cnt = 0;
    float sx = 0.0f, sy = 0.0f;
#pragma unroll
    for (int k = 0; k < NPTS; ++k) {
        if (valid[k]) cnt++;
        float w = valid[k] ? 1.0f : 0.0f;
        sx += px[k] * w;
        sy += py[k] * w;
    }
    float cntf = (float)(cnt > 1 ? cnt : 1);
    float cx_ = sx / cntf, cy_ = sy / cntf;

    unsigned key[NPTS];
#pragma unroll
    for (int k = 0; k < NPTS; ++k) {
        float rx = px[k] - cx_, ry = py[k] - cy_;
        float axx = fabsf(rx), ayy = fabsf(ry);
        float d = fmaxf(axx + ayy, 1e-30f);
        float r = ry * __builtin_amdgcn_rcpf(d);
        float t = (rx >= 0.0f) ? r : ((ry >= 0.0f) ? 2.0f - r : -2.0f - r);
        unsigned u = __float_as_uint(t);
        unsigned ordered = u ^ ((unsigned)((int)u >> 31) | 0x80000000u);
        key[k] = valid[k] ? ((ordered & 0xFFFFFFE0u) | (unsigned)k)
                          : (0xFFFFFF00u | (unsigned)k);
    }

#pragma unroll
    for (int c = 0; c < NET.n; ++c) {
        int lo = NET.lo[c], hi = NET.hi[c];
        bool sw = key[hi] < key[lo];
        unsigned kl = key[lo], kh = key[hi];
        float xl = px[lo], xh = px[hi];
        float yl = py[lo], yh = py[hi];
        key[lo] = sw ? kh : kl;  key[hi] = sw ? kl : kh;
        px[lo]  = sw ? xh : xl;  px[hi]  = sw ? xl : xh;
        py[lo]  = sw ? yh : yl;  py[hi]  = sw ? yl : yh;
    }

    float lastx = 0.0f, lasty = 0.0f;
#pragma unroll
    for (int r = 0; r < NPTS; ++r) {
        bool isLast = (r == cnt - 1);
        lastx = isLast ? px[r] : lastx;
        lasty = isLast ? py[r] : lasty;
    }

    float s = 0.0f;
#pragma unroll
    for (int r = 0; r + 1 < NPTS; ++r) {
        float cr = px[r] * py[r + 1] - px[r + 1] * py[r];
        s += (r + 1 < cnt) ? cr : 0.0f;
    }
    s += (cnt >= 1) ? (lastx * py[0] - px[0] * lasty) : 0.0f;

    float area = 0.5f * fabsf(s);
    return (cnt >= 3) ? area : 0.0f;
}

// ============================================================================
// Fused kernel v2: NO grid-wide sync. Region r (= blockIdx & 63) is fed only
// by waves {w : w & 63 == r} and consumed only by those same waves. Each wave
// arrives at its region's done-counter (RELEASE add, 64 counters spread over
// 256B lines -> ~NB/64 arrivals per line, parallel across lines) and spin-
// polls with relaxed agent loads + s_sleep. This replaces cg::grid.sync()'s
// 2048 serialized same-line RMWs (~225us measured in round 1).
// Safe only under cooperative launch (co-residency) -- enforced on host.
// ============================================================================
__global__ __launch_bounds__(64) void fused_kernel(
    const float* __restrict__ boxes, float* __restrict__ out,
    unsigned* __restrict__ counters, unsigned* __restrict__ done,
    unsigned* __restrict__ regions,
    int m, int n, unsigned reg_cap, unsigned magic, unsigned wpr)
{
    const unsigned n4 = (unsigned)(n >> 2);
    const unsigned NQ = (unsigned)m * n4;            // total j-quads
    const unsigned NT = gridDim.x * 64u;             // total threads
    const unsigned g  = blockIdx.x * 64u + threadIdx.x;
    const unsigned w  = blockIdx.x;                  // wave id (1 wave/block)
    const int lane    = (int)threadIdx.x;            // 0..63
    const unsigned region = w & (NREG - 1);
    const unsigned long long below = (1ull << lane) - 1ull;

    unsigned* ctr = &counters[region * CTR_STRIDE];
    unsigned* dn  = &done[region * CTR_STRIDE];
    unsigned* seg = regions + (size_t)region * reg_cap;

    // ---------------- phase 1: cull ----------------
    for (unsigned q = g; q < NQ; q += NT) {
        unsigned i  = (unsigned)(((unsigned long long)q * magic) >> 32);
        unsigned jq = q - i * n4;
        unsigned j0 = jq * 4u;

        const float* bi = boxes + (size_t)i * 7;
        float xi = bi[0], yi = bi[1];
        float dxi = bi[3], dyi = bi[4];
        float ri = 0.5f * sqrtf(dxi * dxi + dyi * dyi) + 0.005f;

        bool keep[4];
#pragma unroll
        for (int k = 0; k < 4; ++k) {
            const float* bj = boxes + (size_t)(m + j0 + k) * 7;
            float xj = bj[0], yj = bj[1];
            float dxj = bj[3], dyj = bj[4];
            float rj = 0.5f * sqrtf(dxj * dxj + dyj * dyj) + 0.005f;
            float ddx = xi - xj, ddy = yi - yj, rr = ri + rj;
            keep[k] = (ddx * ddx + ddy * ddy) <= rr * rr;
        }

        // zero only non-survivor slots (disjoint from phase-2 writes)
        float* orow = out + (size_t)i * n + j0;
        int km = (keep[0] ? 1 : 0) | (keep[1] ? 2 : 0) |
                 (keep[2] ? 4 : 0) | (keep[3] ? 8 : 0);
        if (km == 0) {
            *(float4*)orow = make_float4(0.0f, 0.0f, 0.0f, 0.0f);
        } else {
#pragma unroll
            for (int k = 0; k < 4; ++k) if (!keep[k]) orow[k] = 0.0f;
        }

        // wave compaction: 4 ballots, one atomic
        unsigned long long mk[4];
        int c[4];
#pragma unroll
        for (int k = 0; k < 4; ++k) {
            mk[k] = __ballot(keep[k]);
            c[k] = __popcll(mk[k]);
        }
        int ctot = c[0] + c[1] + c[2] + c[3];
        if (ctot > 0) {
            unsigned base = 0;
            if (lane == 0)
                base = atomicAdd(ctr, (unsigned)ctot);
            base = (unsigned)__shfl((int)base, 0, 64);
            int pre = 0;
#pragma unroll
            for (int k = 0; k < 4; ++k) {
                if (keep[k]) {
                    int rank = pre + __popcll(mk[k] & below);
                    seg[base + rank] = (i << 12) | (j0 + (unsigned)k);
                }
                pre += c[k];
            }
        }
    }

    // ---------------- per-region arrive + spin ----------------
    // RELEASE: writes back this wave's seg/counter/out stores to the
    // coherence point before the arrival becomes visible.
    if (lane == 0)
        __hip_atomic_fetch_add(dn, 1u, __ATOMIC_RELEASE,
                               __HIP_MEMORY_SCOPE_AGENT);
    // Spin: relaxed agent loads (bypass stale local caches), short sleep.
    // Bounded so a logic bug fails correctness instead of hanging the bench.
    unsigned spins = 0;
    while (__hip_atomic_load(dn, __ATOMIC_RELAXED,
                             __HIP_MEMORY_SCOPE_AGENT) < wpr) {
        __builtin_amdgcn_s_sleep(2);
        if (++spins > (1u << 24)) break;
    }
    __builtin_amdgcn_fence(__ATOMIC_ACQUIRE, "agent");

    // ---------------- phase 2: process survivors ----------------
    unsigned cnt = __hip_atomic_load(ctr, __ATOMIC_RELAXED,
                                     __HIP_MEMORY_SCOPE_AGENT);
    if (cnt > reg_cap) cnt = reg_cap;              // safety clamp
    unsigned slice = w >> 6;                       // this wave's slice [0,wpr)
    for (unsigned t = slice * 64u + (unsigned)lane; t < cnt; t += wpr * 64u) {
        unsigned v = __hip_atomic_load(&seg[t], __ATOMIC_RELAXED,
                                       __HIP_MEMORY_SCOPE_AGENT);
        int i = (int)(v >> 12);
        int j = (int)(v & 4095u);
        const float* A = boxes + (size_t)i * 7;
        const float* B = boxes + (size_t)(m + j) * 7;
        out[(size_t)i * n + j] = pair_area(A, B);
    }
}

// ============================================================================
// Fallback pipeline (verified at 23.65 us) — unchanged.
// ============================================================================
__global__ __launch_bounds__(256) void prep_kernel(
    const float* __restrict__ boxes, float* __restrict__ xs,
    float* __restrict__ ys, float* __restrict__ rs,
    unsigned* __restrict__ counters, int total)
{
    int t = blockIdx.x * blockDim.x + threadIdx.x;
    if (t < NREG * CTR_STRIDE) counters[t] = 0;
    if (t < total) {
        float dx = boxes[(size_t)t * 7 + 3];
        float dy = boxes[(size_t)t * 7 + 4];
        xs[t] = boxes[(size_t)t * 7 + 0];
        ys[t] = boxes[(size_t)t * 7 + 1];
        rs[t] = 0.5f * sqrtf(dx * dx + dy * dy) + 0.005f;
    }
}

__global__ __launch_bounds__(256) void cull_kernel(
    const float* __restrict__ xs, const float* __restrict__ ys,
    const float* __restrict__ rs, float* __restrict__ out,
    unsigned* __restrict__ counters, unsigned* __restrict__ regions,
    int m, int n, unsigned reg_cap)
{
    int jb = blockIdx.x, i = blockIdx.y;
    int tid = threadIdx.x;
    int j = jb * 256 + tid;

    bool keep = false;
    if (j < n) {
        float dx = xs[i] - xs[m + j];
        float dy = ys[i] - ys[m + j];
        float rr = rs[i] + rs[m + j];
        keep = (dx * dx + dy * dy) <= rr * rr;
        out[(size_t)i * n + j] = 0.0f;
    }

    unsigned long long mask = __ballot(keep);
    if (mask == 0ull) return;

    int lane = tid & 63;
    unsigned gwid = ((unsigned)(i * gridDim.x + jb) << 2) | ((unsigned)tid >> 6);
    unsigned region = gwid & (NREG - 1);

    int c = __popcll(mask);
    int lead = __ffsll((unsigned long long)mask) - 1;
    unsigned pos = 0;
    if (lane == lead) pos = atomicAdd(&counters[region * CTR_STRIDE], (unsigned)c);
    pos = (unsigned)__shfl((int)pos, lead, 64);
    if (keep) {
        int rank = __popcll(mask & ((1ull << lane) - 1ull));
        regions[(size_t)region * reg_cap + pos + rank] =
            ((unsigned)i << 12) | (unsigned)j;
    }
}

__global__ __launch_bounds__(64) void process_kernel(
    const float* __restrict__ boxes, float* __restrict__ out,
    const unsigned* __restrict__ counters, const unsigned* __restrict__ regions,
    int m, int n, unsigned reg_cap)
{
    unsigned region = blockIdx.x >> 2;
    unsigned cnt = counters[region * CTR_STRIDE];
    const unsigned* seg = regions + (size_t)region * reg_cap;
    for (unsigned t = ((blockIdx.x & 3u) << 6) | threadIdx.x; t < cnt; t += 256) {
        unsigned v = seg[t];
        int i = (int)(v >> 12);
        int j = (int)(v & 4095u);
        const float* A = boxes + (size_t)i * 7;
        const float* B = boxes + (size_t)(m + j) * 7;
        out[(size_t)i * n + j] = pair_area(A, B);
    }
}

__global__ __launch_bounds__(256) void overlap_kernel(
    const float* __restrict__ boxes, float* __restrict__ out, int m, int n)
{
    int j = blockIdx.x * blockDim.x + threadIdx.x;
    int i = blockIdx.y;
    if (j >= n) return;
    const float* A = boxes + (size_t)i * 7;
    const float* B = boxes + (size_t)(m + j) * 7;
    out[(size_t)i * n + j] = pair_area(A, B);
}

extern "C" void kernel_launch(void* const* d_in, const int* in_sizes, int n_in,
                              void* d_out, int out_size, void* d_ws, size_t ws_size,
                              hipStream_t stream) {
    const float* boxes = (const float*)d_in[0];
    float* out = (float*)d_out;
    int total = in_sizes[0] / 7;   // 3000 boxes
    int m = total / 3;             // 1000
    int n = total - m;             // 2000

    // ---------------- cooperative fused path ----------------
    static int coop_blocks = -2;           // -2 = not queried, -1 = unavailable
    static bool coop_failed = false;
    if (coop_blocks == -2) {
        int occ = 0;
        hipError_t e1 = hipOccupancyMaxActiveBlocksPerMultiprocessor(
            &occ, (const void*)fused_kernel, 64, 0);
        int dev = 0;
        hipGetDevice(&dev);
        hipDeviceProp_t prop;
        hipError_t e2 = hipGetDeviceProperties(&prop, dev);
        coop_blocks = (e1 == hipSuccess && e2 == hipSuccess && occ > 0)
                          ? occ * prop.multiProcessorCount
                          : -1;
    }

    bool coop_ok = !coop_failed && coop_blocks >= 64 &&
                   (n % 4 == 0) && (n <= 4095) && m >= 1;
    unsigned magic = 0, NQ = 0, reg_cap2 = 0;
    int NB = 0;
    if (coop_ok) {
        unsigned d = (unsigned)(n / 4);
        NQ = (unsigned)m * d;
        unsigned long long two32 = 1ull << 32;
        unsigned r = (unsigned)(two32 % d);
        if (r == 0) {
            magic = (unsigned)(two32 / d);
        } else {
            magic = (unsigned)(two32 / d) + 1u;
            if ((unsigned long long)(NQ - 1) * (unsigned long long)(d - r) >= two32)
                coop_ok = false;           // magic-div not exact for this range
        }
        NB = coop_blocks < 2048 ? coop_blocks : 2048;
        NB &= ~63;                         // multiple of 64 (region math)
        if (NB < 64) coop_ok = false;
        if (coop_ok) {
            unsigned nt = (unsigned)NB * 64u;
            unsigned niters = (NQ + nt - 1) / nt;
            reg_cap2 = (unsigned)(NB / 64) * niters * 256u;   // hard upper bound
            size_t need = 2u * (size_t)NREG * CTR_STRIDE * 4 +
                          (size_t)NREG * reg_cap2 * 4;
            if (ws_size < need) coop_ok = false;
        }
    }

    if (coop_ok) {
        unsigned* counters = (unsigned*)d_ws;
        unsigned* done     = (unsigned*)((char*)d_ws + (size_t)NREG * CTR_STRIDE * 4);
        unsigned* regions  = (unsigned*)((char*)d_ws + 2u * (size_t)NREG * CTR_STRIDE * 4);
        unsigned wpr = (unsigned)NB / 64u;
        hipError_t e = hipMemsetAsync(counters, 0,
                                      2u * (size_t)NREG * CTR_STRIDE * 4, stream);
        if (e == hipSuccess) {
            void* args[10];
            args[0] = (void*)&boxes;
            args[1] = (void*)&out;
            args[2] = (void*)&counters;
            args[3] = (void*)&done;
            args[4] = (void*)&regions;
            args[5] = (void*)&m;
            args[6] = (void*)&n;
            args[7] = (void*)&reg_cap2;
            args[8] = (void*)&magic;
            args[9] = (void*)&wpr;
            e = hipLaunchCooperativeKernel((const void*)fused_kernel,
                                           dim3((unsigned)NB), dim3(64),
                                           args, 0, stream);
            if (e == hipSuccess) return;
        }
        coop_failed = true;   // don't retry a failing path
        // fall through to the verified 3-kernel pipeline
    }

    // ---------------- fallback: verified 3-kernel pipeline ----------------
    int bpr = (n + 255) / 256;
    unsigned total_waves = (unsigned)(bpr * m) * 4u;
    unsigned reg_cap = ((total_waves + NREG - 1) / NREG) * 64u;

    size_t ctr_off = 0;
    size_t xs_off  = ctr_off + (size_t)NREG * CTR_STRIDE * 4;
    size_t ys_off  = xs_off + (size_t)total * 4;
    size_t rs_off  = ys_off + (size_t)total * 4;
    size_t reg_off = ((rs_off + (size_t)total * 4) + 255) & ~(size_t)255;
    size_t need    = reg_off + (size_t)NREG * reg_cap * 4;

    if (ws_size < need) {
        dim3 block(256, 1, 1);
        dim3 grid((n + 255) / 256, m, 1);
        hipLaunchKernelGGL(overlap_kernel, grid, block, 0, stream, boxes, out, m, n);
        return;
    }

    unsigned* counters = (unsigned*)((char*)d_ws + ctr_off);
    float* xs = (float*)((char*)d_ws + xs_off);
    float* ys = (float*)((char*)d_ws + ys_off);
    float* rs = (float*)((char*)d_ws + rs_off);
    unsigned* regions = (unsigned*)((char*)d_ws + reg_off);

    int prep_threads = (NREG * CTR_STRIDE > total) ? NREG * CTR_STRIDE : total;
    hipLaunchKernelGGL(prep_kernel, dim3((prep_threads + 255) / 256), dim3(256),
                       0, stream, boxes, xs, ys, rs, counters, total);

    hipLaunchKernelGGL(cull_kernel, dim3(bpr, m, 1), dim3(256), 0, stream,
                       xs, ys, rs, out, counters, regions, m, n, reg_cap);

    hipLaunchKernelGGL(process_kernel, dim3(NREG * 4, 1, 1), dim3(64), 0, stream,
                       boxes, out, counters, regions, m, n, reg_cap);
}

// Round 3
// 19.124 us; speedup vs baseline: 11.6278x; 4.9044x over previous
//
#include <hip/hip_runtime.h>
#include <math.h>

#define EPS 1e-8f
#define NPTS 24
#define MAXN_LDS 2048      // row kernel supports n <= 2048
#define NREG 64            // fallback pipeline worklist regions
#define CTR_STRIDE 64

// ---- constexpr Batcher odd-even mergesort comparator network for NPTS=24 ----
struct Net {
    int n;
    unsigned char lo[256];
    unsigned char hi[256];
};
constexpr Net build_net() {
    Net net{};
    net.n = 0;
    for (int p = 1; p < NPTS; p <<= 1)
        for (int k = p; k >= 1; k >>= 1)
            for (int j = k % p; j + k < NPTS; j += 2 * k)
                for (int i = 0; i < k && i + j + k < NPTS; ++i)
                    if ((i + j) / (2 * p) == (i + j + k) / (2 * p)) {
                        net.lo[net.n] = (unsigned char)(i + j);
                        net.hi[net.n] = (unsigned char)(i + j + k);
                        ++net.n;
                    }
    return net;
}
constexpr Net NET = build_net();

// ---- the verified heavy path: exact area for one pair ----
__device__ __forceinline__ float pair_area(const float* __restrict__ A,
                                           const float* __restrict__ B)
{
    float ax = A[0], ay = A[1], adx = A[3], ady = A[4], ayaw = A[6];
    float bx = B[0], by = B[1], bdx = B[3], bdy = B[4], byaw = B[6];

    float ca = __builtin_cosf(ayaw), sa = __builtin_sinf(ayaw);
    float cb = __builtin_cosf(byaw), sb = __builtin_sinf(byaw);

    const float tx[4] = {0.5f, 0.5f, -0.5f, -0.5f};
    const float ty[4] = {0.5f, -0.5f, -0.5f, 0.5f};

    float cax[4], cay[4], cbx[4], cby[4];
#pragma unroll
    for (int k = 0; k < 4; ++k) {
        float lx = tx[k] * adx, ly = ty[k] * ady;
        cax[k] = lx * ca - ly * sa + ax;
        cay[k] = lx * sa + ly * ca + ay;
        lx = tx[k] * bdx; ly = ty[k] * bdy;
        cbx[k] = lx * cb - ly * sb + bx;
        cby[k] = lx * sb + ly * cb + by;
    }

    float px[NPTS], py[NPTS];
    bool valid[NPTS];

#pragma unroll
    for (int k = 0; k < 4; ++k) {
        float relx = cax[k] - bx, rely = cay[k] - by;
        float rx = relx * cb + rely * sb;
        float ry = -relx * sb + rely * cb;
        valid[k] = (fabsf(rx) <= bdx * 0.5f + 1e-5f) &&
                   (fabsf(ry) <= bdy * 0.5f + 1e-5f);
        px[k] = cax[k]; py[k] = cay[k];
    }
#pragma unroll
    for (int k = 0; k < 4; ++k) {
        float relx = cbx[k] - ax, rely = cby[k] - ay;
        float rx = relx * ca + rely * sa;
        float ry = -relx * sa + rely * ca;
        valid[4 + k] = (fabsf(rx) <= adx * 0.5f + 1e-5f) &&
                       (fabsf(ry) <= ady * 0.5f + 1e-5f);
        px[4 + k] = cbx[k]; py[4 + k] = cby[k];
    }

#pragma unroll
    for (int a = 0; a < 4; ++a) {
        int a2 = (a + 1) & 3;
        float p1x = cax[a], p1y = cay[a];
        float d1x = cax[a2] - p1x, d1y = cay[a2] - p1y;
#pragma unroll
        for (int b = 0; b < 4; ++b) {
            int b2 = (b + 1) & 3;
            float q1x = cbx[b], q1y = cby[b];
            float d2x = cbx[b2] - q1x, d2y = cby[b2] - q1y;
            float denom = d1x * d2y - d1y * d2x;
            bool dok = fabsf(denom) > EPS;
            float safe = dok ? denom : 1.0f;
            float inv = __builtin_amdgcn_rcpf(safe);
            float dqx = q1x - p1x, dqy = q1y - p1y;
            float t = (dqx * d2y - dqy * d2x) * inv;
            float u = (dqx * d1y - dqy * d1x) * inv;
            bool v = dok && (t >= 0.0f) && (t <= 1.0f) && (u >= 0.0f) && (u <= 1.0f);
            int o = 8 + a * 4 + b;
            px[o] = p1x + t * d1x;
            py[o] = p1y + t * d1y;
            valid[o] = v;
        }
    }

    int cnt = 0;
    float sx = 0.0f, sy = 0.0f;
#pragma unroll
    for (int k = 0; k < NPTS; ++k) {
        if (valid[k]) cnt++;
        float w = valid[k] ? 1.0f : 0.0f;
        sx += px[k] * w;
        sy += py[k] * w;
    }
    float cntf = (float)(cnt > 1 ? cnt : 1);
    float cx_ = sx / cntf, cy_ = sy / cntf;

    unsigned key[NPTS];
#pragma unroll
    for (int k = 0; k < NPTS; ++k) {
        float rx = px[k] - cx_, ry = py[k] - cy_;
        float axx = fabsf(rx), ayy = fabsf(ry);
        float d = fmaxf(axx + ayy, 1e-30f);
        float r = ry * __builtin_amdgcn_rcpf(d);
        float t = (rx >= 0.0f) ? r : ((ry >= 0.0f) ? 2.0f - r : -2.0f - r);
        unsigned u = __float_as_uint(t);
        unsigned ordered = u ^ ((unsigned)((int)u >> 31) | 0x80000000u);
        key[k] = valid[k] ? ((ordered & 0xFFFFFFE0u) | (unsigned)k)
                          : (0xFFFFFF00u | (unsigned)k);
    }

#pragma unroll
    for (int c = 0; c < NET.n; ++c) {
        int lo = NET.lo[c], hi = NET.hi[c];
        bool sw = key[hi] < key[lo];
        unsigned kl = key[lo], kh = key[hi];
        float xl = px[lo], xh = px[hi];
        float yl = py[lo], yh = py[hi];
        key[lo] = sw ? kh : kl;  key[hi] = sw ? kl : kh;
        px[lo]  = sw ? xh : xl;  px[hi]  = sw ? xl : xh;
        py[lo]  = sw ? yh : yl;  py[hi]  = sw ? yl : yh;
    }

    float lastx = 0.0f, lasty = 0.0f;
#pragma unroll
    for (int r = 0; r < NPTS; ++r) {
        bool isLast = (r == cnt - 1);
        lastx = isLast ? px[r] : lastx;
        lasty = isLast ? py[r] : lasty;
    }

    float s = 0.0f;
#pragma unroll
    for (int r = 0; r + 1 < NPTS; ++r) {
        float cr = px[r] * py[r + 1] - px[r + 1] * py[r];
        s += (r + 1 < cnt) ? cr : 0.0f;
    }
    s += (cnt >= 1) ? (lastx * py[0] - px[0] * lasty) : 0.0f;

    float area = 0.5f * fabsf(s);
    return (cnt >= 3) ? area : 0.0f;
}

// ============================================================================
// Round-3 kernel: one block per output row i. Fully block-private:
//   - stage j-box SoA (x,y,r) into LDS (coalescing substitute for prep_kernel)
//   - cull 4 j/lane from LDS, float4 zero-stores, ballot-compact survivors
//     into a block-local LDS worklist (1 LDS atomic per wave-iter)
//   - __syncthreads (ordinary block barrier; the ONLY sync in the kernel)
//   - process survivors; round r handled by wave (i+r)&3 to spread the heavy
//     pair_area rounds across SIMDs
// No global atomics, no fences, no cooperative launch, no workspace.
// Worklist cap = MAXN_LDS >= n: overflow impossible for any input.
// ============================================================================
__global__ __launch_bounds__(256) void row_kernel(
    const float* __restrict__ boxes, float* __restrict__ out, int m, int n)
{
    __shared__ float xs_l[MAXN_LDS];
    __shared__ float ys_l[MAXN_LDS];
    __shared__ float rs_l[MAXN_LDS];
    __shared__ unsigned short wl[MAXN_LDS];
    __shared__ unsigned lcnt;

    const int i    = blockIdx.x;
    const int tid  = threadIdx.x;
    const int wv   = tid >> 6;
    const int lane = tid & 63;

    // ---- stage j-box SoA into LDS ----
    for (int t = tid; t < n; t += 256) {
        const float* bj = boxes + (size_t)(m + t) * 7;
        float dx = bj[3], dy = bj[4];
        xs_l[t] = bj[0];
        ys_l[t] = bj[1];
        rs_l[t] = 0.5f * sqrtf(dx * dx + dy * dy) + 0.005f;
    }
    if (tid == 0) lcnt = 0;

    // ---- i-box (broadcast loads) ----
    const float* bi = boxes + (size_t)i * 7;
    float xi = bi[0], yi = bi[1];
    float dxi = bi[3], dyi = bi[4];
    float ri = 0.5f * sqrtf(dxi * dxi + dyi * dyi) + 0.005f;

    __syncthreads();

    const unsigned long long below = (1ull << lane) - 1ull;
    float* orow = out + (size_t)i * n;

    // ---- cull: each wave-iter covers a 256-wide j strip (4 j per lane) ----
    for (int jb = wv * 256; jb < n; jb += 1024) {
        int j0 = jb + lane * 4;                        // 16B-aligned LDS index
        float4 vx = *(const float4*)&xs_l[j0];
        float4 vy = *(const float4*)&ys_l[j0];
        float4 vr = *(const float4*)&rs_l[j0];
        float xj[4] = {vx.x, vx.y, vx.z, vx.w};
        float yj[4] = {vy.x, vy.y, vy.z, vy.w};
        float rj[4] = {vr.x, vr.y, vr.z, vr.w};

        bool keep[4];
#pragma unroll
        for (int k = 0; k < 4; ++k) {
            float ddx = xi - xj[k], ddy = yi - yj[k];
            float rr = ri + rj[k];
            keep[k] = ((j0 + k) < n) &&
                      (ddx * ddx + ddy * ddy) <= rr * rr;
        }

        // zero non-survivor slots (survivor slots written only in phase 2,
        // by this same block -> no cross-agent ordering needed)
        int km = (keep[0] ? 1 : 0) | (keep[1] ? 2 : 0) |
                 (keep[2] ? 4 : 0) | (keep[3] ? 8 : 0);
        if (j0 + 3 < n) {
            if (km == 0) {
                *(float4*)(orow + j0) = make_float4(0.f, 0.f, 0.f, 0.f);
            } else {
#pragma unroll
                for (int k = 0; k < 4; ++k)
                    if (!keep[k]) orow[j0 + k] = 0.0f;
            }
        } else {
#pragma unroll
            for (int k = 0; k < 4; ++k)
                if ((j0 + k) < n && !keep[k]) orow[j0 + k] = 0.0f;
        }

        // ballot-compact survivors into the block-local worklist
        unsigned long long mk[4];
        int c[4];
#pragma unroll
        for (int k = 0; k < 4; ++k) {
            mk[k] = __ballot(keep[k]);
            c[k] = __popcll(mk[k]);
        }
        int ctot = c[0] + c[1] + c[2] + c[3];
        if (ctot > 0) {
            unsigned base = 0;
            if (lane == 0) base = atomicAdd(&lcnt, (unsigned)ctot);
            base = (unsigned)__shfl((int)base, 0, 64);
            int pre = 0;
#pragma unroll
            for (int k = 0; k < 4; ++k) {
                if (keep[k]) {
                    int rank = pre + __popcll(mk[k] & below);
                    wl[base + rank] = (unsigned short)(j0 + k);
                }
                pre += c[k];
            }
        }
    }

    __syncthreads();

    // ---- process survivors; spread rounds across the block's 4 waves ----
    unsigned cnt = lcnt;
    unsigned r = 0;
    for (unsigned base = 0; base < cnt; base += 64, ++r) {
        if ((int)((i + r) & 3u) == wv) {
            unsigned t = base + (unsigned)lane;
            if (t < cnt) {
                int j = (int)wl[t];
                orow[j] = pair_area(bi, boxes + (size_t)(m + j) * 7);
            }
        }
    }
}

// ============================================================================
// Fallback pipeline (verified at 23.65 us) — unchanged.
// ============================================================================
__global__ __launch_bounds__(256) void prep_kernel(
    const float* __restrict__ boxes, float* __restrict__ xs,
    float* __restrict__ ys, float* __restrict__ rs,
    unsigned* __restrict__ counters, int total)
{
    int t = blockIdx.x * blockDim.x + threadIdx.x;
    if (t < NREG * CTR_STRIDE) counters[t] = 0;
    if (t < total) {
        float dx = boxes[(size_t)t * 7 + 3];
        float dy = boxes[(size_t)t * 7 + 4];
        xs[t] = boxes[(size_t)t * 7 + 0];
        ys[t] = boxes[(size_t)t * 7 + 1];
        rs[t] = 0.5f * sqrtf(dx * dx + dy * dy) + 0.005f;
    }
}

__global__ __launch_bounds__(256) void cull_kernel(
    const float* __restrict__ xs, const float* __restrict__ ys,
    const float* __restrict__ rs, float* __restrict__ out,
    unsigned* __restrict__ counters, unsigned* __restrict__ regions,
    int m, int n, unsigned reg_cap)
{
    int jb = blockIdx.x, i = blockIdx.y;
    int tid = threadIdx.x;
    int j = jb * 256 + tid;

    bool keep = false;
    if (j < n) {
        float dx = xs[i] - xs[m + j];
        float dy = ys[i] - ys[m + j];
        float rr = rs[i] + rs[m + j];
        keep = (dx * dx + dy * dy) <= rr * rr;
        out[(size_t)i * n + j] = 0.0f;
    }

    unsigned long long mask = __ballot(keep);
    if (mask == 0ull) return;

    int lane = tid & 63;
    unsigned gwid = ((unsigned)(i * gridDim.x + jb) << 2) | ((unsigned)tid >> 6);
    unsigned region = gwid & (NREG - 1);

    int c = __popcll(mask);
    int lead = __ffsll((unsigned long long)mask) - 1;
    unsigned pos = 0;
    if (lane == lead) pos = atomicAdd(&counters[region * CTR_STRIDE], (unsigned)c);
    pos = (unsigned)__shfl((int)pos, lead, 64);
    if (keep) {
        int rank = __popcll(mask & ((1ull << lane) - 1ull));
        regions[(size_t)region * reg_cap + pos + rank] =
            ((unsigned)i << 12) | (unsigned)j;
    }
}

__global__ __launch_bounds__(64) void process_kernel(
    const float* __restrict__ boxes, float* __restrict__ out,
    const unsigned* __restrict__ counters, const unsigned* __restrict__ regions,
    int m, int n, unsigned reg_cap)
{
    unsigned region = blockIdx.x >> 2;
    unsigned cnt = counters[region * CTR_STRIDE];
    const unsigned* seg = regions + (size_t)region * reg_cap;
    for (unsigned t = ((blockIdx.x & 3u) << 6) | threadIdx.x; t < cnt; t += 256) {
        unsigned v = seg[t];
        int i = (int)(v >> 12);
        int j = (int)(v & 4095u);
        const float* A = boxes + (size_t)i * 7;
        const float* B = boxes + (size_t)(m + j) * 7;
        out[(size_t)i * n + j] = pair_area(A, B);
    }
}

__global__ __launch_bounds__(256) void overlap_kernel(
    const float* __restrict__ boxes, float* __restrict__ out, int m, int n)
{
    int j = blockIdx.x * blockDim.x + threadIdx.x;
    int i = blockIdx.y;
    if (j >= n) return;
    const float* A = boxes + (size_t)i * 7;
    const float* B = boxes + (size_t)(m + j) * 7;
    out[(size_t)i * n + j] = pair_area(A, B);
}

extern "C" void kernel_launch(void* const* d_in, const int* in_sizes, int n_in,
                              void* d_out, int out_size, void* d_ws, size_t ws_size,
                              hipStream_t stream) {
    const float* boxes = (const float*)d_in[0];
    float* out = (float*)d_out;
    int total = in_sizes[0] / 7;   // 3000 boxes
    int m = total / 3;             // 1000
    int n = total - m;             // 2000

    // ---------------- single-dispatch row kernel ----------------
    if (n > 0 && n <= MAXN_LDS && (n % 4) == 0 && m >= 1) {
        hipLaunchKernelGGL(row_kernel, dim3((unsigned)m), dim3(256), 0, stream,
                           boxes, out, m, n);
        return;
    }

    // ---------------- fallback: verified 3-kernel pipeline ----------------
    int bpr = (n + 255) / 256;
    unsigned total_waves = (unsigned)(bpr * m) * 4u;
    unsigned reg_cap = ((total_waves + NREG - 1) / NREG) * 64u;

    size_t ctr_off = 0;
    size_t xs_off  = ctr_off + (size_t)NREG * CTR_STRIDE * 4;
    size_t ys_off  = xs_off + (size_t)total * 4;
    size_t rs_off  = ys_off + (size_t)total * 4;
    size_t reg_off = ((rs_off + (size_t)total * 4) + 255) & ~(size_t)255;
    size_t need    = reg_off + (size_t)NREG * reg_cap * 4;

    if (ws_size < need || n > 4095) {
        dim3 block(256, 1, 1);
        dim3 grid((n + 255) / 256, m, 1);
        hipLaunchKernelGGL(overlap_kernel, grid, block, 0, stream, boxes, out, m, n);
        return;
    }

    unsigned* counters = (unsigned*)((char*)d_ws + ctr_off);
    float* xs = (float*)((char*)d_ws + xs_off);
    float* ys = (float*)((char*)d_ws + ys_off);
    float* rs = (float*)((char*)d_ws + rs_off);
    unsigned* regions = (unsigned*)((char*)d_ws + reg_off);

    int prep_threads = (NREG * CTR_STRIDE > total) ? NREG * CTR_STRIDE : total;
    hipLaunchKernelGGL(prep_kernel, dim3((prep_threads + 255) / 256), dim3(256),
                       0, stream, boxes, xs, ys, rs, counters, total);

    hipLaunchKernelGGL(cull_kernel, dim3(bpr, m, 1), dim3(256), 0, stream,
                       xs, ys, rs, out, counters, regions, m, n, reg_cap);

    hipLaunchKernelGGL(process_kernel, dim3(NREG * 4, 1, 1), dim3(64), 0, stream,
                       boxes, out, counters, regions, m, n, reg_cap);
}